// Round 1
// baseline (272.042 us; speedup 1.0000x reference)
//
#include <hip/hip_runtime.h>
#include <hip/hip_bf16.h>

#define T 50
#define NB 64
#define NS 512
#define START_TAG 48
#define STOP_TAG 49
#define NW 4            // waves per block
#define CHUNK 13        // ceil(T / NW)

static constexpr float LOG2E = 1.4426950408889634f;
static constexpr float LN2F  = 0.6931471805599453f;
#define NEG_BIG (-1.0e38f)

__device__ __forceinline__ float fexp2(float x) {
#if __has_builtin(__builtin_amdgcn_exp2f)
    return __builtin_amdgcn_exp2f(x);   // v_exp_f32 (base-2)
#else
    return exp2f(x);
#endif
}
__device__ __forceinline__ float flog2(float x) {
#if __has_builtin(__builtin_amdgcn_logf)
    return __builtin_amdgcn_logf(x);    // v_log_f32 (base-2)
#else
    return log2f(x);
#endif
}

// One block per batch element. Lane = destination tag j (50 active of 64).
// Wave w owns i-chunk [w*CHUNK, w*CHUNK+CHUNK); per-step partial (max,sum)
// per wave combined through LDS. Everything in log2 domain.
__global__ __launch_bounds__(NW * 64, 1)
void crf_nll(const float* __restrict__ feats,
             const int*   __restrict__ mask,
             const int*   __restrict__ tags,
             const float* __restrict__ trans,
             float* __restrict__ out) {
    const int b    = blockIdx.x;
    const int tid  = threadIdx.x;
    const int w    = tid >> 6;
    const int lane = tid & 63;
    const int j    = lane;
    const int jc   = (j < T) ? j : (T - 1);   // clamp for OOB-safe loads

    __shared__ float s_part[64];      // partition, log2 domain; [T..63] = NEG_BIG
    __shared__ float s_m[NW][T];      // per-wave partial max
    __shared__ float s_s[NW][T];      // per-wave partial sum (base-2)
    __shared__ float s_red[NW];
    __shared__ int   s_lred[NW];

    // ---------------- gold score (all 256 threads, 2 elems each) ------------
    float gsum = 0.f;
    int   lcnt = 0;
    for (int s = tid; s < NS; s += NW * 64) {
        int   m  = mask[b * NS + s];
        int   tg = tags[b * NS + s];
        int   pv = (s == 0) ? START_TAG : tags[b * NS + s - 1];
        float e  = feats[((size_t)b * NS + s) * T + tg];
        float tr = trans[pv * T + tg];
        if (m) { gsum += e + tr; lcnt += 1; }
    }
    #pragma unroll
    for (int off = 32; off > 0; off >>= 1) {
        gsum += __shfl_down(gsum, off, 64);
        lcnt += __shfl_down(lcnt, off, 64);
    }
    if (lane == 0) { s_red[w] = gsum; s_lred[w] = lcnt; }

    // ------------- transition column chunk in registers (log2-scaled) ------
    const int i0 = w * CHUNK;
    float tc[CHUNK];
    #pragma unroll
    for (int k = 0; k < CHUNK; k++) {
        int i = i0 + k;
        tc[k] = (i < T) ? trans[i * T + jc] * LOG2E : 0.f;  // pad rows neutralized via s_part = NEG_BIG
    }

    // ------------- init partition: part[j] = feats[b,0,j] + trans[START,j] --
    if (w == 0) {
        float v = NEG_BIG;
        if (j < T) v = (feats[(size_t)b * NS * T + j] + trans[START_TAG * T + j]) * LOG2E;
        s_part[j] = v;
    }
    __syncthreads();

    float goldb = 0.f;
    if (tid == 0) {
        float g = 0.f; int len = 0;
        #pragma unroll
        for (int k = 0; k < NW; k++) { g += s_red[k]; len += s_lred[k]; }
        int end_id = tags[b * NS + len - 1];
        g += trans[end_id * T + STOP_TAG];
        goldb = g;
    }

    // ---------------- forward recursion over time ---------------------------
    for (int t = 1; t < NS; t++) {
        float f = feats[((size_t)b * NS + t) * T + jc];
        int   m = mask[b * NS + t];

        // phase 1: partial logsumexp over this wave's i-chunk
        float vv[CHUNK];
        float mx = NEG_BIG;
        #pragma unroll
        for (int k = 0; k < CHUNK; k++) {
            vv[k] = s_part[i0 + k] + tc[k];   // broadcast LDS read, conflict-free
            mx = fmaxf(mx, vv[k]);
        }
        float sm = 0.f;
        #pragma unroll
        for (int k = 0; k < CHUNK; k++) sm += fexp2(vv[k] - mx);

        if (j < T) { s_m[w][j] = mx; s_s[w][j] = sm; }
        __syncthreads();   // partials visible; all s_part reads of this step done

        // phase 2: combine NW partials
        float M = NEG_BIG;
        #pragma unroll
        for (int u = 0; u < NW; u++) M = fmaxf(M, s_m[u][jc]);
        float SS = 0.f;
        #pragma unroll
        for (int u = 0; u < NW; u++) SS += s_s[u][jc] * fexp2(s_m[u][jc] - M);
        float cur = M + flog2(SS) + f * LOG2E;

        if (w == 0 && j < T && m) s_part[j] = cur;   // masked update
        __syncthreads();   // new partition visible before next step
    }

    // ---------------- terminal LSE to STOP + output -------------------------
    if (w == 0) {
        float v = (j < T) ? s_part[j] + trans[j * T + STOP_TAG] * LOG2E : NEG_BIG;
        float mx = v;
        #pragma unroll
        for (int off = 32; off > 0; off >>= 1) mx = fmaxf(mx, __shfl_xor(mx, off, 64));
        float e = (j < T) ? fexp2(v - mx) : 0.f;
        #pragma unroll
        for (int off = 32; off > 0; off >>= 1) e += __shfl_xor(e, off, 64);
        if (lane == 0) {
            float fwd = (mx + flog2(e)) * LN2F;      // back to nats
            atomicAdd(out, fwd - goldb);
        }
    }
}

extern "C" void kernel_launch(void* const* d_in, const int* in_sizes, int n_in,
                              void* d_out, int out_size, void* d_ws, size_t ws_size,
                              hipStream_t stream) {
    const float* feats = (const float*)d_in[0];
    const int*   mask  = (const int*)d_in[1];
    const int*   tags  = (const int*)d_in[2];
    const float* trans = (const float*)d_in[3];
    float* out = (float*)d_out;

    hipMemsetAsync(out, 0, sizeof(float) * out_size, stream);  // d_out is poisoned each call
    crf_nll<<<NB, NW * 64, 0, stream>>>(feats, mask, tags, trans, out);
}

// Round 2
// 212.526 us; speedup vs baseline: 1.2800x; 1.2800x over previous
//
#include <hip/hip_runtime.h>
#include <hip/hip_bf16.h>

#define T 50
#define NB 64
#define NS 512
#define START_TAG 48
#define STOP_TAG 49
#define NW 4            // waves per block
#define CHUNK 13        // ceil(T / NW); covers i in [0,52)

static constexpr float LOG2E = 1.4426950408889634f;
static constexpr float LN2F  = 0.6931471805599453f;
#define NEG_BIG (-1.0e38f)

__device__ __forceinline__ float fexp2(float x) { return __builtin_amdgcn_exp2f(x); }  // v_exp_f32
__device__ __forceinline__ float flog2(float x) { return __builtin_amdgcn_logf(x); }   // v_log_f32
__device__ __forceinline__ float bcast_lane(float v, int src) {
    return __uint_as_float(__builtin_amdgcn_readlane(__float_as_uint(v), src));        // v_readlane
}

// One block per batch element, 4 waves. Lane = destination tag j.
// Partition lives in a REGISTER (cur, lane j), redundantly identical in all 4
// waves. Per step: each wave computes a partial sum over its i-chunk using
// v_readlane broadcasts of its own cur (no LDS read, no barrier), writes one
// float to LDS, ONE barrier, then every wave redundantly combines the 4
// partials -> new cur. Single-shift LSE (shift = own prev cur[j]) removes the
// max pass and makes partials directly summable. log2 domain throughout.
__global__ __launch_bounds__(NW * 64, 1)
void crf_nll(const float* __restrict__ feats,
             const int*   __restrict__ mask,
             const int*   __restrict__ tags,
             const float* __restrict__ trans,
             float* __restrict__ out) {
    const int b    = blockIdx.x;
    const int tid  = threadIdx.x;
    const int w    = __builtin_amdgcn_readfirstlane(tid >> 6);
    const int lane = tid & 63;
    const int j    = lane;
    const int jc   = (j < T) ? j : (T - 1);   // clamp: lanes 50..63 mirror j=49 (harmless)

    // [parity][j][col]: 16 B per j -> one ds_read_b128 per lane in combine.
    __shared__ float s_s[2][64][NW];
    __shared__ float s_red[NW];
    __shared__ int   s_lred[NW];

    // ---------------- gold score (one-time) ---------------------------------
    float gsum = 0.f;
    int   lcnt = 0;
    for (int s = tid; s < NS; s += NW * 64) {
        int   m  = mask[b * NS + s];
        int   tg = tags[b * NS + s];
        int   pv = (s == 0) ? START_TAG : tags[b * NS + s - 1];
        float e  = feats[((size_t)b * NS + s) * T + tg];
        float tr = trans[pv * T + tg];
        if (m) { gsum += e + tr; lcnt += 1; }
    }
    #pragma unroll
    for (int off = 32; off > 0; off >>= 1) {
        gsum += __shfl_down(gsum, off, 64);
        lcnt += __shfl_down(lcnt, off, 64);
    }
    if (lane == 0) { s_red[w] = gsum; s_lred[w] = lcnt; }

    // ------------- transition column chunk in registers (log2-scaled) -------
    const int i0 = w * CHUNK;
    float tc[CHUNK];
    #pragma unroll
    for (int k = 0; k < CHUNK; k++) {
        int i = i0 + k;
        // i >= T rows neutralized: -1e38 drives exp2 -> 0
        tc[k] = (i < T) ? trans[i * T + jc] * LOG2E : NEG_BIG;
    }

    // ------------- init partition in registers (all waves identical) --------
    float cur = (feats[(size_t)b * NS * T + jc] + trans[START_TAG * T + jc]) * LOG2E;

    __syncthreads();   // s_red/s_lred visible
    float goldb = 0.f;
    if (tid == 0) {
        float g = 0.f; int len = 0;
        #pragma unroll
        for (int k = 0; k < NW; k++) { g += s_red[k]; len += s_lred[k]; }
        g += trans[tags[b * NS + len - 1] * T + STOP_TAG];
        goldb = g;
    }

    // column swizzle for the partial-sum write: kills 8-way write conflict;
    // read side (b128 of all 4 cols, summed) is order-independent.
    const int col = (w + (j >> 3)) & (NW - 1);

    // prefetch t=1
    float f_n = feats[((size_t)b * NS + 1) * T + jc] * LOG2E;
    int   m_n = mask[b * NS + 1];

    // ---------------- forward recursion: ONE barrier per step ---------------
    for (int t = 1; t < NS; t++) {
        const float f = f_n;
        const int   m = m_n;
        // register prefetch one step ahead -> vmcnt drain at barrier is free
        const int tn = (t + 1 < NS) ? t + 1 : NS - 1;
        f_n = feats[((size_t)b * NS + tn) * T + jc] * LOG2E;
        m_n = mask[b * NS + tn];

        // phase 1: partial sum over this wave's i-chunk, shift = own cur[j]
        float e[CHUNK];
        #pragma unroll
        for (int k = 0; k < CHUNK; k++) {
            float pi = bcast_lane(cur, i0 + k);         // part[i], uniform
            e[k] = fexp2((tc[k] - cur) + pi);           // 2^(part_i + t_ij - part_j)
        }
        // tree sum of 13
        float s01 = e[0] + e[1],  s23 = e[2] + e[3],  s45 = e[4] + e[5];
        float s67 = e[6] + e[7],  s89 = e[8] + e[9],  sab = e[10] + e[11];
        float sm  = ((s01 + s23) + (s45 + s67)) + ((s89 + sab) + e[12]);

        s_s[t & 1][j][col] = sm;
        __syncthreads();

        // phase 2 (redundant in every wave): combine 4 partials
        const float4 p4 = *(const float4*)&s_s[t & 1][j][0];
        float SS = (p4.x + p4.y) + (p4.z + p4.w);
        float nc = cur + flog2(SS) + f;
        cur = m ? nc : cur;
    }

    // ---------------- terminal LSE to STOP + output --------------------------
    if (w == 0) {
        float v = (j < T) ? cur + trans[j * T + STOP_TAG] * LOG2E : NEG_BIG;
        float mx = v;
        #pragma unroll
        for (int off = 32; off > 0; off >>= 1) mx = fmaxf(mx, __shfl_xor(mx, off, 64));
        float ee = (j < T) ? fexp2(v - mx) : 0.f;
        #pragma unroll
        for (int off = 32; off > 0; off >>= 1) ee += __shfl_xor(ee, off, 64);
        if (lane == 0) {
            float fwd = (mx + flog2(ee)) * LN2F;   // back to nats
            atomicAdd(out, fwd - goldb);
        }
    }
}

extern "C" void kernel_launch(void* const* d_in, const int* in_sizes, int n_in,
                              void* d_out, int out_size, void* d_ws, size_t ws_size,
                              hipStream_t stream) {
    const float* feats = (const float*)d_in[0];
    const int*   mask  = (const int*)d_in[1];
    const int*   tags  = (const int*)d_in[2];
    const float* trans = (const float*)d_in[3];
    float* out = (float*)d_out;

    hipMemsetAsync(out, 0, sizeof(float) * out_size, stream);  // d_out is poisoned each call
    crf_nll<<<NB, NW * 64, 0, stream>>>(feats, mask, tags, trans, out);
}

// Round 3
// 198.233 us; speedup vs baseline: 1.3723x; 1.0721x over previous
//
#include <hip/hip_runtime.h>
#include <hip/hip_bf16.h>

#define T 50
#define NB 64
#define NS 512
#define START_TAG 48
#define STOP_TAG 49

static constexpr float LOG2E = 1.4426950408889634f;
static constexpr float LN2F  = 0.6931471805599453f;
#define NEG_BIG (-1.0e38f)

__device__ __forceinline__ float fexp2(float x) { return __builtin_amdgcn_exp2f(x); }  // v_exp_f32
__device__ __forceinline__ float flog2(float x) { return __builtin_amdgcn_logf(x); }   // v_log_f32
__device__ __forceinline__ float bcast_lane(float v, int src) {
    return __uint_as_float(__builtin_amdgcn_readlane(__float_as_uint(v), src));        // v_readlane
}

// ONE WAVE per batch element. Lane = destination tag j. No LDS, no barriers.
//
// Factorization: new_part[j] = lse_i(part[i] + tr[i,j]) + f[j]
//   = s + log2( sum_i 2^(part[i]-s) * E[i][j] ) + f[j]      (log2 domain)
// where E[i][j] = 2^(tr[i][j]*log2e) is TIME-INVARIANT -> precomputed into 50
// VGPRs per lane. Per step: ONE v_exp_f32 (own partition, shift s=lane0's
// partition) + 50 x (v_readlane + v_fmac). Shift safety: cross-tag partition
// spread is bounded by max trans-column diff + feat diff (~+-23 log2 units),
// so 2^(cur[i]-s) stays well inside fp32 range.
__global__ __launch_bounds__(64, 1)
void crf_nll(const float* __restrict__ feats,
             const int*   __restrict__ mask,
             const int*   __restrict__ tags,
             const float* __restrict__ trans,
             float* __restrict__ out) {
    const int b    = blockIdx.x;
    const int lane = threadIdx.x;
    const int j    = lane;
    const int jc   = (j < T) ? j : (T - 1);   // clamp: lanes 50..63 mirror j=49 (unused)

    // ---------------- gold score (one-time, 8 iters) -------------------------
    float gsum = 0.f;
    int   lcnt = 0;
    for (int s = lane; s < NS; s += 64) {
        int   m  = mask[b * NS + s];
        int   tg = tags[b * NS + s];
        int   pv = (s == 0) ? START_TAG : tags[b * NS + s - 1];
        float e  = feats[((size_t)b * NS + s) * T + tg];
        float tr = trans[pv * T + tg];
        if (m) { gsum += e + tr; lcnt += 1; }
    }
    #pragma unroll
    for (int off = 32; off > 0; off >>= 1) {
        gsum += __shfl_down(gsum, off, 64);
        lcnt += __shfl_down(lcnt, off, 64);
    }
    float goldb = 0.f;
    if (lane == 0) {
        goldb = gsum + trans[tags[b * NS + lcnt - 1] * T + STOP_TAG];
    }

    // ------------- E[i] = 2^(trans[i][j]*log2e), time-invariant -------------
    float E[T];
    #pragma unroll
    for (int i = 0; i < T; i++) {
        E[i] = fexp2(trans[i * T + jc] * LOG2E);   // coalesced across lanes
    }

    // ------------- init partition (log2 domain, register) -------------------
    float cur = (feats[(size_t)b * NS * T + jc] + trans[START_TAG * T + jc]) * LOG2E;

    // prefetch pipeline, depth 2 (covers L2/L3 latency vs ~190 cy step)
    float f1 = feats[((size_t)b * NS + 1) * T + jc] * LOG2E;
    int   m1 = mask[b * NS + 1];
    float f2 = feats[((size_t)b * NS + 2) * T + jc] * LOG2E;
    int   m2 = mask[b * NS + 2];

    // ---------------- forward recursion: pure-register steps -----------------
    for (int t = 1; t < NS; t++) {
        const float f = f1;  const int m = m1;
        f1 = f2;  m1 = m2;
        const int tn = (t + 2 < NS) ? t + 2 : NS - 1;
        f2 = feats[((size_t)b * NS + tn) * T + jc] * LOG2E;
        m2 = mask[b * NS + tn];

        const float s0 = bcast_lane(cur, 0);
        const float ex = fexp2(cur - s0);          // one transcendental per step

        float acc[4] = {0.f, 0.f, 0.f, 0.f};
        #pragma unroll
        for (int i = 0; i < T; i++) {
            float p = bcast_lane(ex, i);           // uniform scalar
            acc[i & 3] = fmaf(p, E[i], acc[i & 3]);
        }
        const float SS = (acc[0] + acc[1]) + (acc[2] + acc[3]);
        const float nc = s0 + flog2(SS) + f;
        cur = m ? nc : cur;
    }

    // ---------------- terminal LSE to STOP + output --------------------------
    float v = (j < T) ? cur + trans[j * T + STOP_TAG] * LOG2E : NEG_BIG;
    float mx = v;
    #pragma unroll
    for (int off = 32; off > 0; off >>= 1) mx = fmaxf(mx, __shfl_xor(mx, off, 64));
    float ee = (j < T) ? fexp2(v - mx) : 0.f;
    #pragma unroll
    for (int off = 32; off > 0; off >>= 1) ee += __shfl_xor(ee, off, 64);
    if (lane == 0) {
        float fwd = (mx + flog2(ee)) * LN2F;       // back to nats
        atomicAdd(out, fwd - goldb);
    }
}

extern "C" void kernel_launch(void* const* d_in, const int* in_sizes, int n_in,
                              void* d_out, int out_size, void* d_ws, size_t ws_size,
                              hipStream_t stream) {
    const float* feats = (const float*)d_in[0];
    const int*   mask  = (const int*)d_in[1];
    const int*   tags  = (const int*)d_in[2];
    const float* trans = (const float*)d_in[3];
    float* out = (float*)d_out;

    hipMemsetAsync(out, 0, sizeof(float) * out_size, stream);  // d_out is poisoned each call
    crf_nll<<<NB, 64, 0, stream>>>(feats, mask, tags, trans, out);
}

// Round 5
// 181.141 us; speedup vs baseline: 1.5018x; 1.0944x over previous
//
#include <hip/hip_runtime.h>
#include <hip/hip_bf16.h>

#define T 50
#define NB 64
#define NS 512
#define START_TAG 48
#define STOP_TAG 49
#define NPAIR 25      // T/2 packed f16 pairs

typedef _Float16 half2_t __attribute__((ext_vector_type(2)));

static constexpr float LOG2E = 1.4426950408889634f;
static constexpr float LN2F  = 0.6931471805599453f;
#define NEG_BIG (-1.0e38f)

__device__ __forceinline__ float fexp2(float x) { return __builtin_amdgcn_exp2f(x); }  // v_exp_f32
__device__ __forceinline__ float flog2(float x) { return __builtin_amdgcn_logf(x); }   // v_log_f32
__device__ __forceinline__ float bcastf(float v, int src) {
    return __uint_as_float(__builtin_amdgcn_readlane(__float_as_uint(v), src));
}
__device__ __forceinline__ half2_t bcast_h2(half2_t v, int src) {
    unsigned u = __builtin_amdgcn_readlane(__builtin_bit_cast(unsigned, v), src);
    return __builtin_bit_cast(half2_t, u);
}
__device__ __forceinline__ half2_t pack_h2(float a, float b) {
    return __builtin_bit_cast(half2_t, __builtin_amdgcn_cvt_pkrtz(a, b));  // v_cvt_pkrtz_f16_f32
}

// ONE WAVE per batch element, lane = destination tag j. No LDS, no barriers.
// new_part[j] = s + log2( sum_i 2^(cur[i]-s) * E[i][j] ) + f[j]   (log2 domain)
// E packed as 25 f16 pairs per lane (fits VGPR budget -> no AGPR/scratch
// detour, unlike the 50-fp32 version). Dot product via v_dot2_f32_f16:
// 25 x (v_readlane + v_dot2). ex packed once per step via lane-swap +
// v_cvt_pkrtz. f16 rounding error ~5e-4/step -> O(30) absolute worst-case on
// the final sum, threshold is 3215.
__global__ __launch_bounds__(64, 1)
void crf_nll(const float* __restrict__ feats,
             const int*   __restrict__ mask,
             const int*   __restrict__ tags,
             const float* __restrict__ trans,
             float* __restrict__ out) {
    const int b    = blockIdx.x;
    const int lane = threadIdx.x;
    const int j    = lane;
    const int jc   = (j < T) ? j : (T - 1);   // clamp: lanes 50..63 mirror j=49 (unused)

    // ---------------- gold score (one-time, 8 iters) -------------------------
    float gsum = 0.f;
    int   lcnt = 0;
    for (int s = lane; s < NS; s += 64) {
        int   m  = mask[b * NS + s];
        int   tg = tags[b * NS + s];
        int   pv = (s == 0) ? START_TAG : tags[b * NS + s - 1];
        float e  = feats[((size_t)b * NS + s) * T + tg];
        float tr = trans[pv * T + tg];
        if (m) { gsum += e + tr; lcnt += 1; }
    }
    #pragma unroll
    for (int off = 32; off > 0; off >>= 1) {
        gsum += __shfl_down(gsum, off, 64);
        lcnt += __shfl_down(lcnt, off, 64);
    }
    float goldb = 0.f;
    if (lane == 0) {
        goldb = gsum + trans[tags[b * NS + lcnt - 1] * T + STOP_TAG];
    }

    // -------- E_pk[k] = (2^t[2k][j], 2^t[2k+1][j]) in packed f16 ------------
    half2_t E_pk[NPAIR];
    #pragma unroll
    for (int k = 0; k < NPAIR; k++) {
        float e0 = fexp2(trans[(2 * k)     * T + jc] * LOG2E);
        float e1 = fexp2(trans[(2 * k + 1) * T + jc] * LOG2E);
        E_pk[k] = pack_h2(e0, e1);
    }

    // ------------- init partition (log2 domain, register) -------------------
    float cur = (feats[(size_t)b * NS * T + jc] + trans[START_TAG * T + jc]) * LOG2E;

    // prefetch pipeline, depth 2
    float f1 = feats[((size_t)b * NS + 1) * T + jc] * LOG2E;
    int   m1 = mask[b * NS + 1];
    float f2 = feats[((size_t)b * NS + 2) * T + jc] * LOG2E;
    int   m2 = mask[b * NS + 2];

    // ---------------- forward recursion: pure-register steps -----------------
    for (int t = 1; t < NS; t++) {
        const float f = f1;  const int m = m1;
        f1 = f2;  m1 = m2;
        const int tn = (t + 2 < NS) ? t + 2 : NS - 1;
        f2 = feats[((size_t)b * NS + tn) * T + jc] * LOG2E;
        m2 = mask[b * NS + tn];

        const float s0 = bcastf(cur, 0);
        const float ex = fexp2(cur - s0);            // one transcendental per step
        const float exo = __shfl_xor(ex, 1, 64);     // pair-swap
        const half2_t pk = pack_h2(ex, exo);
        // even lane 2k holds pair (ex[2k], ex[2k+1])

        float acc0 = 0.f, acc1 = 0.f, acc2 = 0.f, acc3 = 0.f;
        #pragma unroll
        for (int k = 0; k < NPAIR; k += 4) {
            acc0 = __builtin_amdgcn_fdot2(bcast_h2(pk, 2 * k),     E_pk[k],     acc0, false);
            if (k + 1 < NPAIR) acc1 = __builtin_amdgcn_fdot2(bcast_h2(pk, 2 * (k + 1)), E_pk[k + 1], acc1, false);
            if (k + 2 < NPAIR) acc2 = __builtin_amdgcn_fdot2(bcast_h2(pk, 2 * (k + 2)), E_pk[k + 2], acc2, false);
            if (k + 3 < NPAIR) acc3 = __builtin_amdgcn_fdot2(bcast_h2(pk, 2 * (k + 3)), E_pk[k + 3], acc3, false);
        }
        const float SS = (acc0 + acc1) + (acc2 + acc3);
        const float nc = s0 + flog2(SS) + f;
        cur = m ? nc : cur;
    }

    // ---------------- terminal LSE to STOP + output --------------------------
    float v = (j < T) ? cur + trans[j * T + STOP_TAG] * LOG2E : NEG_BIG;
    float mx = v;
    #pragma unroll
    for (int off = 32; off > 0; off >>= 1) mx = fmaxf(mx, __shfl_xor(mx, off, 64));
    float ee = (j < T) ? fexp2(v - mx) : 0.f;
    #pragma unroll
    for (int off = 32; off > 0; off >>= 1) ee += __shfl_xor(ee, off, 64);
    if (lane == 0) {
        float fwd = (mx + flog2(ee)) * LN2F;         // back to nats
        atomicAdd(out, fwd - goldb);
    }
}

extern "C" void kernel_launch(void* const* d_in, const int* in_sizes, int n_in,
                              void* d_out, int out_size, void* d_ws, size_t ws_size,
                              hipStream_t stream) {
    const float* feats = (const float*)d_in[0];
    const int*   mask  = (const int*)d_in[1];
    const int*   tags  = (const int*)d_in[2];
    const float* trans = (const float*)d_in[3];
    float* out = (float*)d_out;

    (void)hipMemsetAsync(out, 0, sizeof(float) * out_size, stream);  // d_out is poisoned each call
    crf_nll<<<NB, 64, 0, stream>>>(feats, mask, tags, trans, out);
}

// Round 6
// 151.907 us; speedup vs baseline: 1.7908x; 1.1924x over previous
//
#include <hip/hip_runtime.h>
#include <hip/hip_bf16.h>

#define T 50
#define NB 64
#define NS 512
#define START_TAG 48
#define STOP_TAG 49
#define NCH 8          // time chunks
#define CHL 64         // steps per chunk
#define PITCH 76       // LDS halfword pitch for 64x64 f16 C (bank-spread)

typedef _Float16 f16_t;
typedef _Float16 f16x4 __attribute__((ext_vector_type(4)));
typedef _Float16 f16x8 __attribute__((ext_vector_type(8)));
typedef float    f32x4 __attribute__((ext_vector_type(4)));

static constexpr float LOG2E = 1.4426950408889634f;
static constexpr float LN2F  = 0.6931471805599453f;
static constexpr float S_E   = 6.0f;     // static log2 shift folded out of E
#define NEG_BIG (-1.0e38f)

__device__ __forceinline__ float fexp2(float x) { return __builtin_amdgcn_exp2f(x); }
__device__ __forceinline__ float flog2(float x) { return __builtin_amdgcn_logf(x); }

// =====================================================================
// Kernel 1: per (batch, chunk) compute P_c = prod_{t in chunk} (E * D_t)
// as 64 sequential 64x64x64 f16 MFMA products. E (=2^(trans_l2 - S_E),
// zero-padded outside [0,T)x[0,T)) lives in B-fragment registers the whole
// time. Running product C kept in LDS as raw f16 with an extracted power-
// of-2 shift D (f32 scalar, exact). Wave w owns output row-block [16w,16w+16).
// One barrier per step (double-buffered LDS C + per-step-parity f buffer).
// mask==0 steps are identity: C untouched (cb not toggled), f-pipe advances.
// =====================================================================
__global__ __launch_bounds__(256, 1)
void crf_chunk(const float* __restrict__ feats, const int* __restrict__ mask,
               const float* __restrict__ trans, f16_t* __restrict__ wsC,
               float* __restrict__ wsD) {
    const int c    = blockIdx.x;          // chunk
    const int b    = blockIdx.y;          // batch
    const int tid  = threadIdx.x;
    const int w    = tid >> 6;
    const int lane = tid & 63;
    const int l15  = lane & 15;
    const int q    = lane >> 4;

    __shared__ f16_t sC[2][64 * PITCH];   // C_raw, double-buffered (toggle cb)
    __shared__ float sF[2][64];           // 2^(f_t * log2e) per col, parity s&1
    __shared__ float sMax[2][4];          // per-wave max of C_raw, toggles with cb

    const int t0  = c * CHL + 1;
    const int nst = NS - t0 < CHL ? NS - t0 : CHL;

    // ---- E fragments (B-operand layout: n = 16*c2 + l15, k = 32*kb + q*8 + jj)
    f16x8 Efrag[2][4];
    #pragma unroll
    for (int kb = 0; kb < 2; kb++)
        #pragma unroll
        for (int c2 = 0; c2 < 4; c2++) {
            f16x8 v;
            #pragma unroll
            for (int jj = 0; jj < 8; jj++) {
                int kk = 32 * kb + q * 8 + jj;
                int nn = 16 * c2 + l15;
                float x = 0.f;
                if (kk < T && nn < T) x = fexp2(trans[kk * T + nn] * LOG2E - S_E);
                v[jj] = (f16_t)x;
            }
            Efrag[kb][c2] = v;
        }

    // ---- init: C = I (64x64) in buf 0, max = 1, sF[0] = 2^f(t0)
    for (int idx = tid; idx < 64 * PITCH; idx += 256) sC[0][idx] = (f16_t)0.f;
    if (tid < 64) sC[0][tid * PITCH + tid] = (f16_t)1.f;
    if (tid < 4)  sMax[0][tid] = 1.f;

    float fvA = 0.f, fvB = 0.f;
    if (w == 0) {
        float f0 = (lane < T) ? feats[((size_t)b * NS + t0) * T + lane] : 0.f;
        sF[0][lane] = (lane < T) ? fexp2(f0 * LOG2E) : 0.f;
        int ta = t0 + 1 < NS ? t0 + 1 : NS - 1;
        int tb = t0 + 2 < NS ? t0 + 2 : NS - 1;
        fvA = (lane < T) ? feats[((size_t)b * NS + ta) * T + lane] : 0.f;
        fvB = (lane < T) ? feats[((size_t)b * NS + tb) * T + lane] : 0.f;
    }
    int mk0 = mask[b * NS + t0];
    int mk1 = mask[b * NS + (t0 + 1 < NS ? t0 + 1 : NS - 1)];
    int mk2 = mask[b * NS + (t0 + 2 < NS ? t0 + 2 : NS - 1)];

    float D  = 0.f;
    int   cb = 0;
    __syncthreads();

    for (int s = 0; s < nst; s++) {
        const bool doit = (mk0 != 0);
        mk0 = mk1; mk1 = mk2;
        {
            int tm = t0 + s + 3; tm = tm < NS ? tm : NS - 1;
            mk2 = mask[b * NS + tm];
        }

        if (doit) {
            // renorm shift from previous step's max (clamped so 2^-e fits f16;
            // clamping stays self-consistent because D uses the clamped value)
            float mx4 = fmaxf(fmaxf(sMax[cb][0], sMax[cb][1]),
                              fmaxf(sMax[cb][2], sMax[cb][3]));
            int ebits = (int)((__float_as_uint(mx4) >> 23) & 255) - 127;
            ebits = ebits > 14 ? 14 : (ebits < -14 ? -14 : ebits);
            const float descale = __uint_as_float((unsigned)(127 - ebits) << 23);
            D += (float)ebits + S_E;
            const f16_t dsc = (f16_t)descale;

            // A fragments: rows m = 16w + l15, k = 32kb + q*8 + 0..7 (f16 LDS)
            f16x8 A[2];
            #pragma unroll
            for (int kb = 0; kb < 2; kb++) {
                const int base = (16 * w + l15) * PITCH + 32 * kb + q * 8;
                f16x4 lo = *(const f16x4*)&sC[cb][base];
                f16x4 hi = *(const f16x4*)&sC[cb][base + 4];
                f16x8 a;
                #pragma unroll
                for (int z = 0; z < 4; z++) { a[z] = lo[z] * dsc; a[z + 4] = hi[z] * dsc; }
                A[kb] = a;
            }

            // 8 MFMAs: C_next rows [16w,16w+16) x all 4 col-blocks
            f32x4 acc[4];
            #pragma unroll
            for (int c2 = 0; c2 < 4; c2++) {
                acc[c2] = __builtin_amdgcn_mfma_f32_16x16x32_f16(A[0], Efrag[0][c2],
                                                                 (f32x4){0.f,0.f,0.f,0.f}, 0, 0, 0);
                acc[c2] = __builtin_amdgcn_mfma_f32_16x16x32_f16(A[1], Efrag[1][c2],
                                                                 acc[c2], 0, 0, 0);
            }

            // column scale by 2^f, track max, store f16 to other buffer
            const int nb2 = cb ^ 1;
            float wmax = 0.f;
            #pragma unroll
            for (int c2 = 0; c2 < 4; c2++) {
                const float cs = sF[s & 1][16 * c2 + l15];
                #pragma unroll
                for (int r = 0; r < 4; r++) {
                    float v = acc[c2][r] * cs;
                    wmax = fmaxf(wmax, v);
                    sC[nb2][(16 * w + 4 * q + r) * PITCH + 16 * c2 + l15] = (f16_t)v;
                }
            }
            #pragma unroll
            for (int off = 32; off > 0; off >>= 1)
                wmax = fmaxf(wmax, __shfl_xor(wmax, off, 64));
            if (lane == 0) sMax[cb ^ 1][w] = wmax;
        }

        // f staging for step s+1 (always advances, mask-independent)
        if (w == 0) {
            sF[(s + 1) & 1][lane] = (lane < T) ? fexp2(fvA * LOG2E) : 0.f;
            fvA = fvB;
            int tl = t0 + s + 3; tl = tl < NS ? tl : NS - 1;
            fvB = (lane < T) ? feats[((size_t)b * NS + tl) * T + lane] : 0.f;
        }
        __syncthreads();
        if (doit) cb ^= 1;
    }

    // ---- store C_raw (f16, row-major 64x64) + shift D
    {
        const int row  = tid >> 2;
        const int col0 = (tid & 3) * 16;
        const f16_t* src = &sC[cb][row * PITCH + col0];
        f16_t* dst = wsC + ((size_t)(b * NCH + c)) * 4096 + row * 64 + col0;
        #pragma unroll
        for (int kk = 0; kk < 4; kk++)
            *(unsigned long long*)(dst + kk * 4) = *(const unsigned long long*)(src + kk * 4);
        if (tid == 0) wsD[b * NCH + c] = D;
    }
}

// =====================================================================
// Kernel 2: one wave per batch. part = v0; for each chunk: part = part (x) P_c
// via exp-domain dot against the stored f16 matrix + shift. Then terminal LSE
// to STOP and gold score; atomicAdd the NLL contribution.
// =====================================================================
__global__ __launch_bounds__(64, 1)
void crf_combine(const float* __restrict__ feats, const int* __restrict__ mask,
                 const int* __restrict__ tags, const float* __restrict__ trans,
                 const f16_t* __restrict__ wsC, const float* __restrict__ wsD,
                 float* __restrict__ out) {
    const int b    = blockIdx.x;
    const int lane = threadIdx.x;

    __shared__ f16_t sM[4096];
    __shared__ float sEx[64];

    // ---------------- gold score ----------------
    float gsum = 0.f;
    int   lcnt = 0;
    for (int s = lane; s < NS; s += 64) {
        int   m  = mask[b * NS + s];
        int   tg = tags[b * NS + s];
        int   pv = (s == 0) ? START_TAG : tags[b * NS + s - 1];
        float e  = feats[((size_t)b * NS + s) * T + tg];
        float tr = trans[pv * T + tg];
        if (m) { gsum += e + tr; lcnt += 1; }
    }
    #pragma unroll
    for (int off = 32; off > 0; off >>= 1) {
        gsum += __shfl_down(gsum, off, 64);
        lcnt += __shfl_down(lcnt, off, 64);
    }
    float goldb = 0.f;
    if (lane == 0) goldb = gsum + trans[tags[b * NS + lcnt - 1] * T + STOP_TAG];

    // ---------------- part init (t = 0), log2 domain ----------------
    float part = (lane < T)
        ? (feats[(size_t)b * NS * T + lane] + trans[START_TAG * T + lane]) * LOG2E
        : NEG_BIG;

    // ---------------- chunks ----------------
    for (int c = 0; c < NCH; c++) {
        const f16_t* src = wsC + (size_t)(b * NCH + c) * 4096;
        #pragma unroll
        for (int kk = 0; kk < 8; kk++)
            ((int4*)&sM[lane * 64])[kk] = ((const int4*)(src + lane * 64))[kk];

        float s = part;
        #pragma unroll
        for (int off = 32; off > 0; off >>= 1) s = fmaxf(s, __shfl_xor(s, off, 64));
        float ex = fexp2(part - s);
        sEx[lane] = ex;
        __syncthreads();

        float a0 = 0.f, a1 = 0.f;
        #pragma unroll
        for (int i = 0; i < T; i += 2) {
            a0 += sEx[i]     * (float)sM[i * 64 + lane];
            a1 += sEx[i + 1] * (float)sM[(i + 1) * 64 + lane];
        }
        part = s + wsD[b * NCH + c] + flog2(a0 + a1);
        __syncthreads();
    }

    // ---------------- terminal LSE to STOP + output ----------------
    float v = (lane < T) ? part + trans[lane * T + STOP_TAG] * LOG2E : NEG_BIG;
    float mx = v;
    #pragma unroll
    for (int off = 32; off > 0; off >>= 1) mx = fmaxf(mx, __shfl_xor(mx, off, 64));
    float ee = (lane < T) ? fexp2(v - mx) : 0.f;
    #pragma unroll
    for (int off = 32; off > 0; off >>= 1) ee += __shfl_xor(ee, off, 64);
    if (lane == 0) {
        float fwd = (mx + flog2(ee)) * LN2F;   // back to nats
        atomicAdd(out, fwd - goldb);
    }
}

extern "C" void kernel_launch(void* const* d_in, const int* in_sizes, int n_in,
                              void* d_out, int out_size, void* d_ws, size_t ws_size,
                              hipStream_t stream) {
    const float* feats = (const float*)d_in[0];
    const int*   mask  = (const int*)d_in[1];
    const int*   tags  = (const int*)d_in[2];
    const float* trans = (const float*)d_in[3];
    float* out = (float*)d_out;

    f16_t* wsC = (f16_t*)d_ws;
    float* wsD = (float*)((char*)d_ws + (size_t)NB * NCH * 4096 * sizeof(f16_t));

    (void)hipMemsetAsync(out, 0, sizeof(float) * out_size, stream);
    crf_chunk<<<dim3(NCH, NB), 256, 0, stream>>>(feats, mask, trans, wsC, wsD);
    crf_combine<<<NB, 64, 0, stream>>>(feats, mask, tags, trans, wsC, wsD, out);
}

// Round 7
// 139.924 us; speedup vs baseline: 1.9442x; 1.0856x over previous
//
#include <hip/hip_runtime.h>
#include <hip/hip_bf16.h>

#define T 50
#define NB 64
#define NS 512
#define START_TAG 48
#define STOP_TAG 49
#define NCH 8          // time chunks
#define CHL 64         // steps per chunk
#define PITCH 76       // LDS halfword pitch for 64x64 f16 C (bank-spread)

typedef _Float16 f16_t;
typedef _Float16 f16x2 __attribute__((ext_vector_type(2)));
typedef _Float16 f16x4 __attribute__((ext_vector_type(4)));
typedef _Float16 f16x8 __attribute__((ext_vector_type(8)));
typedef float    f32x4 __attribute__((ext_vector_type(4)));

static constexpr float LOG2E = 1.4426950408889634f;
static constexpr float LN2F  = 0.6931471805599453f;
static constexpr float S_E   = 6.0f;     // static log2 shift folded out of E
#define NEG_BIG (-1.0e38f)

__device__ __forceinline__ float fexp2(float x) { return __builtin_amdgcn_exp2f(x); }
__device__ __forceinline__ float flog2(float x) { return __builtin_amdgcn_logf(x); }
__device__ __forceinline__ f16x2 bcast_h2(f16x2 v, int src) {
    unsigned u = __builtin_amdgcn_readlane(__builtin_bit_cast(unsigned, v), src);
    return __builtin_bit_cast(f16x2, u);
}
__device__ __forceinline__ f16x2 pack_h2(float a, float b) {
    return __builtin_bit_cast(f16x2, __builtin_amdgcn_cvt_pkrtz(a, b));
}

// =====================================================================
// Kernel 1: per (batch, chunk) compute P_c = prod_{t in chunk} (E * D_t)
// as 64 sequential 64x64x64 f16 MFMA products. ALL global data (feats
// block -> sF, masks -> sMk) preloaded before the loop so the per-step
// barrier drains nothing. Result stored TRANSPOSED (C^T row-major f16)
// for the combine kernel's coalesced per-lane column reads.
// =====================================================================
__global__ __launch_bounds__(256, 1)
void crf_chunk(const float* __restrict__ feats, const int* __restrict__ mask,
               const float* __restrict__ trans, f16_t* __restrict__ wsCt,
               float* __restrict__ wsD) {
    const int c    = blockIdx.x;          // chunk
    const int b    = blockIdx.y;          // batch
    const int tid  = threadIdx.x;
    const int w    = tid >> 6;
    const int lane = tid & 63;
    const int l15  = lane & 15;
    const int q    = lane >> 4;

    __shared__ f16_t sC[2][64 * PITCH];   // C_raw, double-buffered (toggle cb)
    __shared__ float sF[CHL][64];         // 2^(f_t * log2e) per step/col (preloaded)
    __shared__ int   sMk[CHL];            // masks (preloaded)
    __shared__ float sMax[2][4];          // per-wave max of C_raw, toggles with cb

    const int t0  = c * CHL + 1;
    const int nst = NS - t0 < CHL ? NS - t0 : CHL;

    // ---- E fragments (B-operand layout: n = 16*c2 + l15, k = 32*kb + q*8 + jj)
    f16x8 Efrag[2][4];
    #pragma unroll
    for (int kb = 0; kb < 2; kb++)
        #pragma unroll
        for (int c2 = 0; c2 < 4; c2++) {
            f16x8 v;
            #pragma unroll
            for (int jj = 0; jj < 8; jj++) {
                int kk = 32 * kb + q * 8 + jj;
                int nn = 16 * c2 + l15;
                float x = 0.f;
                if (kk < T && nn < T) x = fexp2(fmaf(trans[kk * T + nn], LOG2E, -S_E));
                v[jj] = (f16_t)x;
            }
            Efrag[kb][c2] = v;
        }

    // ---- bulk preload: feats block (exp2 once) + masks; zero global in loop
    for (int r = w; r < CHL; r += 4) {
        int tl = t0 + r; tl = tl < NS ? tl : NS - 1;
        float fv = (lane < T && r < nst) ? feats[((size_t)b * NS + tl) * T + lane] : 0.f;
        sF[r][lane] = (lane < T && r < nst) ? fexp2(fv * LOG2E) : 0.f;
    }
    if (tid < CHL) {
        int tl = t0 + tid; tl = tl < NS ? tl : NS - 1;
        sMk[tid] = (tid < nst) ? mask[b * NS + tl] : 0;
    }

    // ---- init: C = I (64x64) in buf 0, max = 1
    for (int idx = tid; idx < 64 * PITCH; idx += 256) sC[0][idx] = (f16_t)0.f;
    if (tid < 64) sC[0][tid * PITCH + tid] = (f16_t)1.f;
    if (tid < 4)  sMax[0][tid] = 1.f;
    __syncthreads();

    float D  = 0.f;
    int   cb = 0;
    int   mk = sMk[0];

    for (int s = 0; s < nst; s++) {
        const bool doit = (mk != 0);
        mk = (s + 1 < CHL) ? sMk[s + 1] : 0;   // prefetch next mask (LDS)

        if (doit) {
            // renorm shift from previous step's max (clamped so 2^-e fits f16)
            float mx4 = fmaxf(fmaxf(sMax[cb][0], sMax[cb][1]),
                              fmaxf(sMax[cb][2], sMax[cb][3]));
            int ebits = (int)((__float_as_uint(mx4) >> 23) & 255) - 127;
            ebits = ebits > 14 ? 14 : (ebits < -14 ? -14 : ebits);
            const float descale = __uint_as_float((unsigned)(127 - ebits) << 23);
            D += (float)ebits + S_E;
            const f16_t dsc = (f16_t)descale;

            // A fragments: rows m = 16w + l15, k = 32kb + q*8 + 0..7 (f16 LDS)
            f16x8 A[2];
            #pragma unroll
            for (int kb = 0; kb < 2; kb++) {
                const int base = (16 * w + l15) * PITCH + 32 * kb + q * 8;
                f16x4 lo = *(const f16x4*)&sC[cb][base];
                f16x4 hi = *(const f16x4*)&sC[cb][base + 4];
                f16x8 a;
                #pragma unroll
                for (int z = 0; z < 4; z++) { a[z] = lo[z] * dsc; a[z + 4] = hi[z] * dsc; }
                A[kb] = a;
            }

            // 8 MFMAs: C_next rows [16w,16w+16) x all 4 col-blocks
            f32x4 acc[4];
            #pragma unroll
            for (int c2 = 0; c2 < 4; c2++) {
                acc[c2] = __builtin_amdgcn_mfma_f32_16x16x32_f16(A[0], Efrag[0][c2],
                                                                 (f32x4){0.f,0.f,0.f,0.f}, 0, 0, 0);
                acc[c2] = __builtin_amdgcn_mfma_f32_16x16x32_f16(A[1], Efrag[1][c2],
                                                                 acc[c2], 0, 0, 0);
            }

            // column scale by 2^f (LDS, preloaded), track max, store f16
            const int nb2 = cb ^ 1;
            float wmax = 0.f;
            #pragma unroll
            for (int c2 = 0; c2 < 4; c2++) {
                const float cs = sF[s][16 * c2 + l15];
                #pragma unroll
                for (int r = 0; r < 4; r++) {
                    float v = acc[c2][r] * cs;
                    wmax = fmaxf(wmax, v);
                    sC[nb2][(16 * w + 4 * q + r) * PITCH + 16 * c2 + l15] = (f16_t)v;
                }
            }
            #pragma unroll
            for (int off = 32; off > 0; off >>= 1)
                wmax = fmaxf(wmax, __shfl_xor(wmax, off, 64));
            if (lane == 0) sMax[cb ^ 1][w] = wmax;
        }

        __syncthreads();
        if (doit) cb ^= 1;
    }

    // ---- store C TRANSPOSED: wsCt[.. + col*64 + row] = C[row][col]
    {
        const int col = tid >> 2;
        const int r0  = (tid & 3) << 4;
        unsigned short tmp[16];
        #pragma unroll
        for (int r = 0; r < 16; r++)
            tmp[r] = __builtin_bit_cast(unsigned short, sC[cb][(r0 + r) * PITCH + col]);
        f16_t* dst = wsCt + ((size_t)(b * NCH + c)) * 4096 + col * 64 + r0;
        ((int4*)dst)[0] = *(const int4*)&tmp[0];
        ((int4*)dst)[1] = *(const int4*)&tmp[8];
        if (tid == 0) wsD[b * NCH + c] = D;
    }
}

// =====================================================================
// Kernel 2: one wave per batch, no LDS, no barriers. Lane j holds column j
// of each chunk matrix (= C^T row j, contiguous 128 B) in registers,
// register-prefetched one chunk ahead. part = part (x) P_c via true-max
// shift + packed-f16 dot2 (25 x readlane + v_dot2_f32_f16).
// =====================================================================
__global__ __launch_bounds__(64, 1)
void crf_combine(const float* __restrict__ feats, const int* __restrict__ mask,
                 const int* __restrict__ tags, const float* __restrict__ trans,
                 const f16_t* __restrict__ wsCt, const float* __restrict__ wsD,
                 float* __restrict__ out) {
    const int b    = blockIdx.x;
    const int lane = threadIdx.x;

    // ---------------- gold score ----------------
    float gsum = 0.f;
    int   lcnt = 0;
    for (int s = lane; s < NS; s += 64) {
        int   m  = mask[b * NS + s];
        int   tg = tags[b * NS + s];
        int   pv = (s == 0) ? START_TAG : tags[b * NS + s - 1];
        float e  = feats[((size_t)b * NS + s) * T + tg];
        float tr = trans[pv * T + tg];
        if (m) { gsum += e + tr; lcnt += 1; }
    }
    #pragma unroll
    for (int off = 32; off > 0; off >>= 1) {
        gsum += __shfl_down(gsum, off, 64);
        lcnt += __shfl_down(lcnt, off, 64);
    }
    float goldb = 0.f;
    if (lane == 0) goldb = gsum + trans[tags[b * NS + lcnt - 1] * T + STOP_TAG];

    // ---------------- part init (t = 0), log2 domain ----------------
    float part = (lane < T)
        ? (feats[(size_t)b * NS * T + lane] + trans[START_TAG * T + lane]) * LOG2E
        : NEG_BIG;

    // ---------------- shifts + chunk 0 matrix into registers ----------------
    float Dv[NCH];
    #pragma unroll
    for (int c = 0; c < NCH; c++) Dv[c] = wsD[b * NCH + c];

    int cur[32], nxt[32];
    {
        const f16_t* src = wsCt + (size_t)b * NCH * 4096 + lane * 64;
        #pragma unroll
        for (int kk = 0; kk < 8; kk++)
            *(int4*)&cur[4 * kk] = ((const int4*)src)[kk];
    }

    #pragma unroll
    for (int c = 0; c < NCH; c++) {
        if (c + 1 < NCH) {
            const f16_t* src = wsCt + (size_t)(b * NCH + c + 1) * 4096 + lane * 64;
            #pragma unroll
            for (int kk = 0; kk < 8; kk++)
                *(int4*)&nxt[4 * kk] = ((const int4*)src)[kk];
        }

        // true-max shift (required: ex must fit packed f16)
        float sft = part;
        #pragma unroll
        for (int off = 32; off > 0; off >>= 1) sft = fmaxf(sft, __shfl_xor(sft, off, 64));
        float ex  = fexp2(part - sft);
        float exo = __shfl_xor(ex, 1, 64);
        f16x2 pk  = pack_h2(ex, exo);     // even lane 2k holds (ex[2k], ex[2k+1])

        float a0 = 0.f, a1 = 0.f, a2 = 0.f, a3 = 0.f;
        #pragma unroll
        for (int k = 0; k < 25; k += 4) {
            a0 = __builtin_amdgcn_fdot2(bcast_h2(pk, 2 * k), __builtin_bit_cast(f16x2, cur[k]), a0, false);
            if (k + 1 < 25) a1 = __builtin_amdgcn_fdot2(bcast_h2(pk, 2 * (k + 1)), __builtin_bit_cast(f16x2, cur[k + 1]), a1, false);
            if (k + 2 < 25) a2 = __builtin_amdgcn_fdot2(bcast_h2(pk, 2 * (k + 2)), __builtin_bit_cast(f16x2, cur[k + 2]), a2, false);
            if (k + 3 < 25) a3 = __builtin_amdgcn_fdot2(bcast_h2(pk, 2 * (k + 3)), __builtin_bit_cast(f16x2, cur[k + 3]), a3, false);
        }
        part = sft + Dv[c] + flog2((a0 + a1) + (a2 + a3));

        if (c + 1 < NCH) {
            #pragma unroll
            for (int kk = 0; kk < 32; kk++) cur[kk] = nxt[kk];
        }
    }

    // ---------------- terminal LSE to STOP + output ----------------
    float v = (lane < T) ? part + trans[lane * T + STOP_TAG] * LOG2E : NEG_BIG;
    float mx = v;
    #pragma unroll
    for (int off = 32; off > 0; off >>= 1) mx = fmaxf(mx, __shfl_xor(mx, off, 64));
    float ee = (lane < T) ? fexp2(v - mx) : 0.f;
    #pragma unroll
    for (int off = 32; off > 0; off >>= 1) ee += __shfl_xor(ee, off, 64);
    if (lane == 0) {
        float fwd = (mx + flog2(ee)) * LN2F;   // back to nats
        atomicAdd(out, fwd - goldb);
    }
}

extern "C" void kernel_launch(void* const* d_in, const int* in_sizes, int n_in,
                              void* d_out, int out_size, void* d_ws, size_t ws_size,
                              hipStream_t stream) {
    const float* feats = (const float*)d_in[0];
    const int*   mask  = (const int*)d_in[1];
    const int*   tags  = (const int*)d_in[2];
    const float* trans = (const float*)d_in[3];
    float* out = (float*)d_out;

    f16_t* wsCt = (f16_t*)d_ws;
    float* wsD  = (float*)((char*)d_ws + (size_t)NB * NCH * 4096 * sizeof(f16_t));

    (void)hipMemsetAsync(out, 0, sizeof(float) * out_size, stream);
    crf_chunk<<<dim3(NCH, NB), 256, 0, stream>>>(feats, mask, trans, wsCt, wsD);
    crf_combine<<<NB, 64, 0, stream>>>(feats, mask, tags, trans, wsCt, wsD, out);
}